// Round 12
// baseline (109.032 us; speedup 1.0000x reference)
//
#include <hip/hip_runtime.h>
#include <math.h>

#define N 4096
#define E 96
#define H 6
#define DH 16
#define G 64
#define CMAX 128          // max supported group size
#define KSTR 19           // LDS row stride (r6/r11-proven attention reads)
#define FSTR 104          // bf16 elems per staged feats row (96 + 8 pad)
#define NW 8
#define NT 512

typedef __attribute__((ext_vector_type(8))) short short8;
typedef __attribute__((ext_vector_type(4))) float f32x4;
typedef __attribute__((ext_vector_type(4))) unsigned u32x4;

static __device__ __forceinline__ unsigned short f2bf(float f) {
    unsigned u = __builtin_bit_cast(unsigned, f);
    return (unsigned short)((u + 0x7fffu + ((u >> 16) & 1u)) >> 16);   // RNE
}
static __device__ __forceinline__ unsigned pack2(float lo, float hi) {
    return (unsigned)f2bf(lo) | ((unsigned)f2bf(hi) << 16);
}

// ---------------- K1: per (group, part): bucket + stage feats(bf16) + MFMA proj
// part p: 0=q (scaled), 1=k, 2=v. B-fragments packed from global w_in (L2-hot).
__global__ __launch_bounds__(NT, 4) void qkv_kernel(const float* __restrict__ feats,
                                                    const int* __restrict__ grp,
                                                    const float* __restrict__ w_in,
                                                    const float* __restrict__ b_in,
                                                    int* __restrict__ cnts,
                                                    int* __restrict__ bucketg,
                                                    float* __restrict__ Qc,
                                                    float* __restrict__ Kc,
                                                    float* __restrict__ Vc) {
    __shared__ short fA[CMAX * FSTR];     // 26.6 KB
    __shared__ int   bucket[CMAX];
    __shared__ unsigned long long smask[64];
    __shared__ int   scount[64];
    __shared__ int   soffs[64];
    __shared__ int   scnt;

    int g = blockIdx.x & 63;
    int p = blockIdx.x >> 6;              // 0..2
    int tid = threadIdx.x, lane = tid & 63, wv = tid >> 6;

    // ---- Phase A: per-chunk ballot masks (deterministic; r6-verified)
    #pragma unroll
    for (int c8 = 0; c8 < 8; ++c8) {
        int cc = wv * 8 + c8;
        bool mt = (grp[(cc << 6) + lane] == g);
        unsigned long long mask = __ballot(mt);
        if (lane == 0) { smask[cc] = mask; scount[cc] = __popcll(mask); }
    }
    __syncthreads();

    // ---- Phase B: wave 0 exclusive scan
    if (wv == 0) {
        int v = scount[lane];
        int x = v;
        #pragma unroll
        for (int o = 1; o < 64; o <<= 1) {
            int y = __shfl_up(x, o, 64);
            if (lane >= o) x += y;
        }
        soffs[lane] = x - v;
        if (lane == 63) scnt = x;
    }
    __syncthreads();

    int cnt = scnt; if (cnt > CMAX) cnt = CMAX;

    // ---- Phase C: deterministic scatter
    #pragma unroll
    for (int c8 = 0; c8 < 8; ++c8) {
        int cc = wv * 8 + c8;
        unsigned long long mask = smask[cc];
        if ((mask >> lane) & 1ULL) {
            int pos = soffs[cc] + __popcll(mask & ((1ULL << lane) - 1ULL));
            if (pos < CMAX) bucket[pos] = (cc << 6) + lane;
        }
    }
    __syncthreads();

    // ---- handoff for attn kernel (p==0 blocks only; values deterministic)
    if (p == 0) {
        if (tid == 0) cnts[g] = cnt;
        if (tid < CMAX) bucketg[g * CMAX + tid] = bucket[tid];
    }

    // ---- stage fA: group's feats rows as bf16 (r10-verified)
    {
        int srow = tid >> 2, sq = tid & 3;
        if (srow < cnt) {
            const float4* src = (const float4*)(feats + bucket[srow] * E + sq * 24);
            unsigned* dst = (unsigned*)(fA + srow * FSTR + sq * 24);
            #pragma unroll
            for (int t = 0; t < 6; ++t) {
                float4 v = src[t];
                dst[2 * t]     = pack2(v.x, v.y);
                dst[2 * t + 1] = pack2(v.z, v.w);
            }
        }
    }
    __syncthreads();

    // ---- MFMA jobs: (row-tile, head); B packed from global w_in
    int lr = lane & 15, kg = lane >> 4;
    int rowtiles = (cnt + 15) >> 4;
    int njobs = rowtiles * 6;
    float* outb = (p == 0) ? Qc : (p == 1) ? Kc : Vc;
    float scale = (p == 0) ? 0.25f : 1.0f;      // 1/sqrt(16) folded into q
    #pragma unroll 1
    for (int jj = wv; jj < njobs; jj += NW) {
        int rt = jj / 6, ho = jj % 6;
        int c = p * E + ho * DH + lr;           // w_in row = output col
        const float4* wr = (const float4*)(w_in + c * E);
        const short* ab = fA + (rt * 16 + lr) * FSTR + kg * 8;
        f32x4 acc = {0.f, 0.f, 0.f, 0.f};
        #pragma unroll
        for (int kc = 0; kc < 3; ++kc) {
            float4 b0 = wr[kc * 8 + kg * 2];
            float4 b1 = wr[kc * 8 + kg * 2 + 1];
            u32x4 bw = { pack2(b0.x, b0.y), pack2(b0.z, b0.w),
                         pack2(b1.x, b1.y), pack2(b1.z, b1.w) };
            acc = __builtin_amdgcn_mfma_f32_16x16x32_bf16(*(const short8*)(ab + kc * 32),
                    __builtin_bit_cast(short8, bw), acc, 0, 0, 0);
        }
        float bias = b_in[c];
        float* ob = outb + ((ho * G + g) * CMAX) * 16;
        #pragma unroll
        for (int r = 0; r < 4; ++r) {
            int row = rt * 16 + kg * 4 + r;     // bucket slot (D row; m89-verified)
            if (row < cnt) ob[row * 16 + lr] = (acc[r] + bias) * scale;
        }
    }
}

// ---------------- K2: per (group, head): stage Q/K/V rows -> LDS, r11 attention
__global__ __launch_bounds__(NT, 4) void attn_kernel(const int* __restrict__ cnts,
                                                     const int* __restrict__ bucketg,
                                                     const float* __restrict__ Qc,
                                                     const float* __restrict__ Kc,
                                                     const float* __restrict__ Vc,
                                                     const float* __restrict__ w_out,
                                                     const float* __restrict__ w_cls,
                                                     float* __restrict__ part) {
    __shared__ float kh[CMAX * KSTR];
    __shared__ float vh[CMAX * KSTR];
    __shared__ float qh[CMAX * KSTR];
    __shared__ float ps[NW * 2 * CMAX];
    __shared__ int   sbk[CMAX];
    __shared__ float wfh[DH];
    __shared__ int   scnt_s;

    int g = blockIdx.x & 63;
    int h = blockIdx.x >> 6;
    int tid = threadIdx.x, lane = tid & 63, wv = tid >> 6;

    if (tid == 0) { int c = cnts[g]; scnt_s = (c > CMAX) ? CMAX : c; }
    if (tid >= 64 && tid < 192) sbk[tid - 64] = bucketg[g * CMAX + (tid - 64)];
    if (wv == 7) {                        // folded classifier head slice (r6-verified)
        int dd = lane & 15, u4 = lane >> 4;
        float s = 0.f;
        for (int u = u4 * 24; u < u4 * 24 + 24; ++u)
            s += w_cls[u] * w_out[u * E + h * DH + dd];
        s += __shfl_xor(s, 16, 64);
        s += __shfl_xor(s, 32, 64);
        if (lane < DH) wfh[lane] = s;
    }
    __syncthreads();
    int cnt = scnt_s;

    // ---- stage rows (coalesced float4 from compact global layout)
    {
        int row = tid >> 2, q = tid & 3;
        long base = ((long)(h * G + g) * CMAX + row) * 16 + q * 4;
        if (row < cnt) {
            float4 kv = *(const float4*)(Kc + base);
            float4 vv = *(const float4*)(Vc + base);
            float4 qv = *(const float4*)(Qc + base);
            #pragma unroll
            for (int t = 0; t < 4; ++t) {
                kh[row * KSTR + q * 4 + t] = ((const float*)&kv)[t];
                vh[row * KSTR + q * 4 + t] = ((const float*)&vv)[t];
                qh[row * KSTR + q * 4 + t] = ((const float*)&qv)[t];
            }
        } else {
            #pragma unroll
            for (int t = 0; t < 4; ++t) vh[row * KSTR + q * 4 + t] = 0.f;
        }
    }
    __syncthreads();

    // ---- attention: 2 rows/iter, shared K/V reads (r11-verbatim)
    float* ps0 = ps + (2 * wv) * CMAX;
    float* ps1 = ps + (2 * wv + 1) * CMAX;
    for (int j0 = wv; j0 < cnt; j0 += 2 * NW) {
        int j1 = j0 + NW;
        bool has1 = (j1 < cnt);
        int j1r = has1 ? j1 : j0;

        float qv0[16], qv1[16];
        #pragma unroll
        for (int e = 0; e < 16; ++e) {
            qv0[e] = qh[j0 * KSTR + e];
            qv1[e] = qh[j1r * KSTR + e];
        }

        float a00 = 0.f, a10 = 0.f;
        #pragma unroll
        for (int e = 0; e < 16; ++e) {
            float kl = kh[lane * KSTR + e];
            a00 += qv0[e] * kl;
            a10 += qv1[e] * kl;
        }
        float s00 = (lane < cnt) ? a00 : -INFINITY;
        float s10 = (lane < cnt) ? a10 : -INFINITY;
        float s01 = -INFINITY, s11 = -INFINITY;
        if (cnt > 64) {
            float a01 = 0.f, a11 = 0.f;
            #pragma unroll
            for (int e = 0; e < 16; ++e) {
                float kl = kh[(64 + lane) * KSTR + e];
                a01 += qv0[e] * kl;
                a11 += qv1[e] * kl;
            }
            s01 = (64 + lane < cnt) ? a01 : -INFINITY;
            s11 = (64 + lane < cnt) ? a11 : -INFINITY;
        }

        float m0 = fmaxf(s00, s01), m1 = fmaxf(s10, s11);
        #pragma unroll
        for (int o = 32; o >= 1; o >>= 1) {
            m0 = fmaxf(m0, __shfl_xor(m0, o, 64));
            m1 = fmaxf(m1, __shfl_xor(m1, o, 64));
        }
        float p00 = __expf(s00 - m0), p10 = __expf(s10 - m1);
        float p01 = (cnt > 64) ? __expf(s01 - m0) : 0.f;
        float p11 = (cnt > 64) ? __expf(s11 - m1) : 0.f;
        float l0 = p00 + p01, l1 = p10 + p11;
        #pragma unroll
        for (int o = 32; o >= 1; o >>= 1) {
            l0 += __shfl_xor(l0, o, 64);
            l1 += __shfl_xor(l1, o, 64);
        }
        ps0[lane] = p00; ps0[64 + lane] = p01;
        ps1[lane] = p10; ps1[64 + lane] = p11;

        int mm4 = lane >> 4, dd = lane & 15;
        float acc0 = 0.f, acc1 = 0.f;
        #pragma unroll
        for (int k = 0; k < 16; ++k) {
            int m2 = mm4 + 4 * k;
            float vv = vh[m2 * KSTR + dd];
            acc0 += ps0[m2] * vv;
            acc1 += ps1[m2] * vv;
        }
        if (cnt > 64) {
            #pragma unroll
            for (int k = 16; k < 32; ++k) {
                int m2 = mm4 + 4 * k;
                float vv = vh[m2 * KSTR + dd];
                acc0 += ps0[m2] * vv;
                acc1 += ps1[m2] * vv;
            }
        }
        acc0 += __shfl_xor(acc0, 16, 64); acc1 += __shfl_xor(acc1, 16, 64);
        acc0 += __shfl_xor(acc0, 32, 64); acc1 += __shfl_xor(acc1, 32, 64);

        float pt0 = (acc0 / l0) * wfh[dd];
        float pt1 = (acc1 / l1) * wfh[dd];
        pt0 += __shfl_xor(pt0, 1, 64);  pt1 += __shfl_xor(pt1, 1, 64);
        pt0 += __shfl_xor(pt0, 2, 64);  pt1 += __shfl_xor(pt1, 2, 64);
        pt0 += __shfl_xor(pt0, 4, 64);  pt1 += __shfl_xor(pt1, 4, 64);
        pt0 += __shfl_xor(pt0, 8, 64);  pt1 += __shfl_xor(pt1, 8, 64);
        if (lane == 0) {
            part[sbk[j0] * 8 + h] = pt0;            // exactly-once, no atomic
            if (has1) part[sbk[j1] * 8 + h] = pt1;
        }
    }
}

// ---------------- K3: sum 6 head partials + folded bias, sigmoid
__global__ __launch_bounds__(512) void sigmoid_kernel(const float* __restrict__ part,
                                                      const float* __restrict__ w_cls,
                                                      const float* __restrict__ b_out,
                                                      const float* __restrict__ b_cls,
                                                      float* __restrict__ out) {
    __shared__ float sbias;
    int tid = threadIdx.x;
    if (tid < 64) {
        float s = w_cls[tid] * b_out[tid];
        if (tid < 32) s += w_cls[tid + 64] * b_out[tid + 64];
        #pragma unroll
        for (int o = 32; o >= 1; o >>= 1) s += __shfl_xor(s, o, 64);
        if (tid == 0) sbias = s + b_cls[0];
    }
    __syncthreads();
    int i = blockIdx.x * 512 + tid;
    const float4* p = (const float4*)(part + i * 8);
    float4 u = p[0], v = p[1];
    float s = u.x + u.y + u.z + u.w + v.x + v.y + sbias;
    out[i] = 1.f / (1.f + __expf(-s));
}

extern "C" void kernel_launch(void* const* d_in, const int* in_sizes, int n_in,
                              void* d_out, int out_size, void* d_ws, size_t ws_size,
                              hipStream_t stream) {
    const float* feats = (const float*)d_in[0];
    const int*   grp   = (const int*)  d_in[1];
    const float* w_in  = (const float*)d_in[2];
    const float* b_in  = (const float*)d_in[3];
    const float* w_out = (const float*)d_in[4];
    const float* b_out = (const float*)d_in[5];
    const float* w_cls = (const float*)d_in[6];
    const float* b_cls = (const float*)d_in[7];
    float* out = (float*)d_out;

    float* part   = (float*)d_ws;                 // N*8
    int* cnts     = (int*)(part + N * 8);         // 64
    int* bucketg  = cnts + 64;                    // 64*128
    float* Qc     = (float*)(bucketg + G * CMAX); // 6*64*128*16 each
    float* Kc     = Qc + H * G * CMAX * 16;
    float* Vc     = Kc + H * G * CMAX * 16;

    qkv_kernel<<<G * 3, NT, 0, stream>>>(feats, grp, w_in, b_in, cnts, bucketg, Qc, Kc, Vc);
    attn_kernel<<<G * H, NT, 0, stream>>>(cnts, bucketg, Qc, Kc, Vc, w_out, w_cls, part);
    sigmoid_kernel<<<N / 512, 512, 0, stream>>>(part, w_cls, b_out, b_cls, out);
}